// Round 4
// baseline (487.236 us; speedup 1.0000x reference)
//
#include <hip/hip_runtime.h>
#include <hip/hip_bf16.h>

typedef __attribute__((ext_vector_type(8))) short short8;
typedef __attribute__((ext_vector_type(4))) float float4v;

// fp32 -> bf16 round-to-nearest-even (finite inputs only)
__device__ inline unsigned short f2bf(float f) {
    union { float f; unsigned int i; } c; c.f = f;
    unsigned int r = c.i + 0x7FFFu + ((c.i >> 16) & 1u);
    return (unsigned short)(r >> 16);
}

// ---------------------------------------------------------------------------
// Kernel 1: transpose encoder part of attn_w (fp32 rows 512..1535, [k][d])
// into W_t [d][k] (512 x 1024 bf16) so MFMA B-fragments are contiguous in k.
// ---------------------------------------------------------------------------
__global__ void k_transpose(const float* __restrict__ W,
                            unsigned short* __restrict__ Wt) {
    int idx = blockIdx.x * 256 + threadIdx.x;   // 65536 threads: 512 d x 128 kgroups
    int d  = idx & 511;
    int kg = idx >> 9;                          // k = kg*8 .. kg*8+7
    short8 v;
#pragma unroll
    for (int j = 0; j < 8; j++)
        v[j] = (short)f2bf(W[(size_t)(512 + kg * 8 + j) * 512 + d]); // coalesced over d
    *(short8*)(Wt + (size_t)d * 1024 + kg * 8) = v;
}

// ---------------------------------------------------------------------------
// Kernel 2: hb[b][d] = hidden[b,:] @ W[0:512, d] + bias[d]  (fp32)
// grid (4 d-groups, 64 b) x 128 thr -> 256 blocks, coalesced W reads.
// ---------------------------------------------------------------------------
__global__ void k_hb(const float* __restrict__ hidden,
                     const float* __restrict__ W,
                     const float* __restrict__ bias,
                     float* __restrict__ hb) {
    int b = blockIdx.y, dg = blockIdx.x, tid = threadIdx.x;
    int d = dg * 128 + tid;
    __shared__ float h[512];
    for (int k = tid; k < 512; k += 128) h[k] = hidden[b * 512 + k];
    __syncthreads();
    float a = 0.f;
#pragma unroll 16
    for (int k = 0; k < 512; k++)
        a += h[k] * W[(size_t)k * 512 + d];
    hb[b * 512 + d] = a + bias[d];
}

// ---------------------------------------------------------------------------
// Kernel 3: fused GEMM(enc @ W_e) + tanh(.+hb) . v  reduction.
// Grid (16 s-tiles, 64 b), block 512 = 8 waves. Wave w: d in [w*64,(w+1)*64).
// acc = 4mt x 4nt x f32x4 = 64 AGPR/lane. All global loads prefetched:
//   B-frags 1 chunk ahead (regs), A 2 chunks ahead (regs) -> LDS 1 ahead.
// ---------------------------------------------------------------------------
__launch_bounds__(512, 2)
__global__ void k_main(const float* __restrict__ enc,
                       const unsigned short* __restrict__ Wt,
                       const float* __restrict__ hb,
                       const float* __restrict__ vvec,
                       float* __restrict__ att) {
    const int b    = blockIdx.y;
    const int s0   = blockIdx.x * 64;
    const int tid  = threadIdx.x;
    const int wave = tid >> 6;
    const int lane = tid & 63;
    const int col  = lane & 15;   // n (B) / m (A) index
    const int quad = lane >> 4;   // k-group: k = quad*8 + j

    __shared__ unsigned short As[2][64][72];   // 64 rows x 64 k bf16, +8 pad
    __shared__ float red[8][64];

    // A staging map: thread t -> row r = t>>3, segment seg = t&7 (8 floats)
    const int r   = tid >> 3;
    const int seg = tid & 7;
    int s = s0 + r; if (s > 999) s = 999;          // dup rows masked at output
    const float* arow = enc + ((size_t)(b * 1000 + s) * 1024) + seg * 8;

    // B fragment base: W_t[d][k], d = wave*64 + nt*16 + col
    const unsigned short* bbase = Wt + (size_t)(wave * 64 + col) * 1024 + quad * 8;

    float4v acc[4][4];
#pragma unroll
    for (int mt = 0; mt < 4; mt++)
#pragma unroll
        for (int nt = 0; nt < 4; nt++)
            acc[mt][nt] = float4v{0.f, 0.f, 0.f, 0.f};

    short8  bf[2][8];      // B-frag ping-pong: [parity][nt*2+ks]
    float4v sp[2][2];      // A-stage ping-pong: [parity][half]

    // ---- prologue ----
    // stage A chunk 0 directly into As[0]
    {
        float4v a0 = *(const float4v*)(arow);
        float4v a1 = *(const float4v*)(arow + 4);
        short8 wv;
#pragma unroll
        for (int j = 0; j < 4; j++) { wv[j] = (short)f2bf(a0[j]); wv[j + 4] = (short)f2bf(a1[j]); }
        *(short8*)&As[0][r][seg * 8] = wv;
    }
    // A chunk 1 into sp[0]
    sp[0][0] = *(const float4v*)(arow + 64);
    sp[0][1] = *(const float4v*)(arow + 68);
    // B chunk 0 into bf[0]
#pragma unroll
    for (int nt = 0; nt < 4; nt++)
#pragma unroll
        for (int ks = 0; ks < 2; ks++)
            bf[0][nt * 2 + ks] = *(const short8*)(bbase + (size_t)nt * 16384 + ks * 32);
    __syncthreads();

    // ---- main K loop: 16 chunks of 64 ----
#pragma unroll
    for (int c = 0; c < 16; c++) {
        const int cur = c & 1, nxt = cur ^ 1;

        // prefetch B chunk c+1 into regs (used next iteration)
        if (c < 15) {
#pragma unroll
            for (int nt = 0; nt < 4; nt++)
#pragma unroll
                for (int ks = 0; ks < 2; ks++)
                    bf[nxt][nt * 2 + ks] =
                        *(const short8*)(bbase + (size_t)nt * 16384 + (c + 1) * 64 + ks * 32);
        }
        // prefetch A chunk c+2 into regs (staged to LDS next iteration)
        if (c < 14) {
            sp[nxt][0] = *(const float4v*)(arow + (c + 2) * 64);
            sp[nxt][1] = *(const float4v*)(arow + (c + 2) * 64 + 4);
        }

        // A fragments from LDS
        short8 af[2][4];
#pragma unroll
        for (int ks = 0; ks < 2; ks++)
#pragma unroll
            for (int mt = 0; mt < 4; mt++)
                af[ks][mt] = *(const short8*)&As[cur][mt * 16 + col][ks * 32 + quad * 8];

#pragma unroll
        for (int ks = 0; ks < 2; ks++)
#pragma unroll
            for (int mt = 0; mt < 4; mt++)
#pragma unroll
                for (int nt = 0; nt < 4; nt++)
                    acc[mt][nt] = __builtin_amdgcn_mfma_f32_16x16x32_bf16(
                        af[ks][mt], bf[cur][nt * 2 + ks], acc[mt][nt], 0, 0, 0);

        // stage A chunk c+1 (loaded last iteration) into the other LDS buffer
        if (c < 15) {
            short8 wv;
#pragma unroll
            for (int j = 0; j < 4; j++) {
                wv[j]     = (short)f2bf(sp[cur][0][j]);
                wv[j + 4] = (short)f2bf(sp[cur][1][j]);
            }
            *(short8*)&As[nxt][r][seg * 8] = wv;
        }
        __syncthreads();
    }

    // ---- epilogue: att_partial[m] += tanh(e + hb) * v over this wave's 64 d's
    float vv[4], hbv[4];
#pragma unroll
    for (int nt = 0; nt < 4; nt++) {
        int d = wave * 64 + nt * 16 + col;
        vv[nt]  = vvec[d];
        hbv[nt] = hb[b * 512 + d];
    }
    float rs[4][4];   // [mt][rg] -> row m = mt*16 + quad*4 + rg
#pragma unroll
    for (int mt = 0; mt < 4; mt++)
#pragma unroll
        for (int rg = 0; rg < 4; rg++) rs[mt][rg] = 0.f;

#pragma unroll
    for (int mt = 0; mt < 4; mt++)
#pragma unroll
        for (int nt = 0; nt < 4; nt++)
#pragma unroll
            for (int rg = 0; rg < 4; rg++) {
                float e = acc[mt][nt][rg] + hbv[nt];
                float t = 1.f - 2.f / (__expf(2.f * e) + 1.f);   // tanh
                rs[mt][rg] += t * vv[nt];
            }

#pragma unroll
    for (int mt = 0; mt < 4; mt++)
#pragma unroll
        for (int rg = 0; rg < 4; rg++) {
            float x = rs[mt][rg];
            x += __shfl_xor(x, 1);
            x += __shfl_xor(x, 2);
            x += __shfl_xor(x, 4);
            x += __shfl_xor(x, 8);
            rs[mt][rg] = x;
        }

    if (col == 0) {
#pragma unroll
        for (int mt = 0; mt < 4; mt++)
#pragma unroll
            for (int rg = 0; rg < 4; rg++)
                red[wave][mt * 16 + quad * 4 + rg] = rs[mt][rg];
    }
    __syncthreads();
    if (tid < 64) {
        float sum = red[0][tid] + red[1][tid] + red[2][tid] + red[3][tid]
                  + red[4][tid] + red[5][tid] + red[6][tid] + red[7][tid];
        int ss = s0 + tid;
        if (ss < 1000) att[b * 1000 + ss] = sum;
    }
}

// ---------------------------------------------------------------------------
// Kernel 4: row softmax over S=1000, fp32 out.
// ---------------------------------------------------------------------------
__global__ void k_softmax(const float* __restrict__ att,
                          float* __restrict__ out) {
    int b = blockIdx.x, tid = threadIdx.x;
    __shared__ float sm[4], ss[4];
    float x[4], mx = -1e30f;
#pragma unroll
    for (int i = 0; i < 4; i++) {
        int s = tid + 256 * i;
        x[i] = (s < 1000) ? att[b * 1000 + s] : -1e30f;
        mx = fmaxf(mx, x[i]);
    }
    for (int off = 1; off < 64; off <<= 1) mx = fmaxf(mx, __shfl_xor(mx, off));
    if ((tid & 63) == 0) sm[tid >> 6] = mx;
    __syncthreads();
    mx = fmaxf(fmaxf(sm[0], sm[1]), fmaxf(sm[2], sm[3]));

    float ex[4], se = 0.f;
#pragma unroll
    for (int i = 0; i < 4; i++) {
        ex[i] = __expf(x[i] - mx);
        if (tid + 256 * i >= 1000) ex[i] = 0.f;
        se += ex[i];
    }
    for (int off = 1; off < 64; off <<= 1) se += __shfl_xor(se, off);
    if ((tid & 63) == 0) ss[tid >> 6] = se;
    __syncthreads();
    se = ss[0] + ss[1] + ss[2] + ss[3];
    float inv = 1.f / se;
#pragma unroll
    for (int i = 0; i < 4; i++) {
        int s = tid + 256 * i;
        if (s < 1000) out[b * 1000 + s] = ex[i] * inv;
    }
}

// ---------------------------------------------------------------------------
extern "C" void kernel_launch(void* const* d_in, const int* in_sizes, int n_in,
                              void* d_out, int out_size, void* d_ws, size_t ws_size,
                              hipStream_t stream) {
    const float* hidden = (const float*)d_in[0]; // [64,512]
    const float* enc    = (const float*)d_in[1]; // [64,1000,1024]
    const float* attn_w = (const float*)d_in[2]; // [1536,512]
    const float* attn_b = (const float*)d_in[3]; // [512]
    const float* v      = (const float*)d_in[4]; // [512]
    float* out = (float*)d_out;                  // [64,1000]

    char* ws = (char*)d_ws;
    unsigned short* Wt = (unsigned short*)ws;                       // 1 MB bf16
    float* hb  = (float*)(ws + (1 << 20));                          // 128 KB
    float* att = (float*)(ws + (1 << 20) + (128 << 10));            // 250 KB

    k_transpose<<<256, 256, 0, stream>>>(attn_w, Wt);
    k_hb<<<dim3(4, 64), 128, 0, stream>>>(hidden, attn_w, attn_b, hb);
    k_main<<<dim3(16, 64), 512, 0, stream>>>(enc, Wt, hb, v, att);
    k_softmax<<<64, 256, 0, stream>>>(att, out);
}